// Round 1
// baseline (41.379 us; speedup 1.0000x reference)
//
#include <hip/hip_runtime.h>

// PositionLossVal: offset [4,18,512,512] f32, optical_flow [4,8,512,512] f32 -> scalar f32.
// Per pixel: x=off[i], y=off[i+9] (i<9); u=flow[j], v=flow[j+1] (j<4).
// min_dis = inside ? perp : min(d1,d2); min over j, mean over i, sum over b,h,w, /(h*w).

#define HW_BITS 18
#define HW_ (1 << HW_BITS)          // 512*512
#define NOFF 9
#define NFLOW 4
#define NPIX (4 * HW_)              // 1,048,576 pixels
#define BLK 256
#define NTHREADS (NPIX / 4)         // float4 per thread
#define GRID1 (NTHREADS / BLK)      // 1024 blocks

__global__ __launch_bounds__(BLK)
void pos_loss_main(const float* __restrict__ off, const float* __restrict__ flow,
                   float* __restrict__ partial)
{
    const int t  = blockIdx.x * BLK + threadIdx.x;   // 0..262143
    const int g  = t << 2;                           // first pixel of this thread's float4
    const int b  = g >> HW_BITS;
    const int hw = g & (HW_ - 1);
    const float* offb = off  + ((size_t)b * (2 * NOFF)) * HW_ + hw;
    const float* flb  = flow + ((size_t)b * 8) * HW_ + hw;

    // Flow channels 0..4 (u = ch j, v = ch j+1), vectorized 16B loads.
    float4 us[NFLOW + 1];
#pragma unroll
    for (int j = 0; j <= NFLOW; ++j)
        us[j] = *reinterpret_cast<const float4*>(flb + (size_t)j * HW_);

    // Hoist per-(pixel,j) invariants out of the 9-deep i loop.
    float u_[4][NFLOW], v_[4][NFLOW], uv_[4][NFLOW], r_[4][NFLOW], rs_[4][NFLOW];
#pragma unroll
    for (int j = 0; j < NFLOW; ++j) {
        const float up[4] = {us[j].x, us[j].y, us[j].z, us[j].w};
        const float vp[4] = {us[j + 1].x, us[j + 1].y, us[j + 1].z, us[j + 1].w};
#pragma unroll
        for (int p = 0; p < 4; ++p) {
            const float u = up[p], v = vp[p];
            const float uu = fmaf(u, u, v * v);          // u*u + v*v
            u_[p][j]  = u;
            v_[p][j]  = v;
            uv_[p][j] = u * v;
            r_[p][j]  = __builtin_amdgcn_rcpf(uu);       // 1/(u^2+v^2)
            rs_[p][j] = __builtin_amdgcn_rsqf(uu);       // 1/sqrt(u^2+v^2)
        }
    }

    float acc = 0.f;
#pragma unroll
    for (int i = 0; i < NOFF; ++i) {
        const float4 x4 = *reinterpret_cast<const float4*>(offb + (size_t)i * HW_);
        const float4 y4 = *reinterpret_cast<const float4*>(offb + (size_t)(i + NOFF) * HW_);
        const float xp[4] = {x4.x, x4.y, x4.z, x4.w};
        const float yp[4] = {y4.x, y4.y, y4.z, y4.w};
#pragma unroll
        for (int p = 0; p < 4; ++p) {
            const float x  = xp[p], y = yp[p];
            const float x2 = x * x;
            const float d1 = __builtin_amdgcn_sqrtf(fmaf(y, y, x2));   // sqrt(x^2+y^2)
            float m = 1e30f;
#pragma unroll
            for (int j = 0; j < NFLOW; ++j) {
                const float u = u_[p][j], v = v_[p][j];
                // x0 = (u*x*x + u*v*y) / (u*u+v*v)
                const float x0 = fmaf(u, x2, uv_[p][j] * y) * r_[p][j];
                // inside  <=>  min(0,u) <= x0 <= max(0,u)  <=>  x0*(x0-u) <= 0
                const float ins  = x0 * (x0 - u);
                const float perp = fabsf(fmaf(-u, y, v * x)) * rs_[p][j];
                const float dx = x - u, dy = y - v;
                const float d2  = __builtin_amdgcn_sqrtf(fmaf(dy, dy, dx * dx));
                const float end = fminf(d1, d2);
                const float md  = (ins <= 0.f) ? perp : end;
                m = fminf(m, md);
            }
            acc += m;
        }
    }

    // Block reduction: wave64 shuffle tree -> LDS -> one partial per block.
#pragma unroll
    for (int o = 32; o > 0; o >>= 1) acc += __shfl_down(acc, o, 64);
    __shared__ float sm[BLK / 64];
    const int lane = threadIdx.x & 63, wid = threadIdx.x >> 6;
    if (lane == 0) sm[wid] = acc;
    __syncthreads();
    if (threadIdx.x == 0)
        partial[blockIdx.x] = sm[0] + sm[1] + sm[2] + sm[3];
}

__global__ __launch_bounds__(BLK)
void pos_loss_reduce(const float* __restrict__ partial, float* __restrict__ out)
{
    float s = 0.f;
#pragma unroll
    for (int k = 0; k < GRID1 / BLK; ++k)
        s += partial[k * BLK + (int)threadIdx.x];
#pragma unroll
    for (int o = 32; o > 0; o >>= 1) s += __shfl_down(s, o, 64);
    __shared__ float sm[BLK / 64];
    const int lane = threadIdx.x & 63, wid = threadIdx.x >> 6;
    if (lane == 0) sm[wid] = s;
    __syncthreads();
    if (threadIdx.x == 0)
        out[0] = (sm[0] + sm[1] + sm[2] + sm[3]) * (1.0f / (9.0f * (float)HW_));
}

extern "C" void kernel_launch(void* const* d_in, const int* in_sizes, int n_in,
                              void* d_out, int out_size, void* d_ws, size_t ws_size,
                              hipStream_t stream) {
    const float* offset = (const float*)d_in[0];   // [4,18,512,512]
    const float* flow   = (const float*)d_in[1];   // [4,8,512,512]
    float* partial = (float*)d_ws;                 // GRID1 floats
    float* out     = (float*)d_out;                // 1 float

    pos_loss_main<<<GRID1, BLK, 0, stream>>>(offset, flow, partial);
    pos_loss_reduce<<<1, BLK, 0, stream>>>(partial, out);
}

// Round 2
// 28.366 us; speedup vs baseline: 1.4588x; 1.4588x over previous
//
#include <hip/hip_runtime.h>

// PositionLossVal: offset [4,18,512,512] f32, optical_flow [4,8,512,512] f32 -> scalar f32.
// Per pixel: x=off[i], y=off[i+9] (i<9); u=flow[j], v=flow[j+1] (j<4).
// md = inside ? perp : min(d1,d2); min over j, mean over i, sum over b,h,w, /(h*w).
// Optimization: min over j computed in squared domain -> one sqrt per (pixel,i).

#define HW_BITS 18
#define HW_ (1 << HW_BITS)          // 512*512
#define NOFF 9
#define NFLOW 4
#define NPIX (4 * HW_)              // 1,048,576 pixels (one thread each)
#define BLK 256
#define GRID1 (NPIX / BLK)          // 4096 blocks

__global__ __launch_bounds__(BLK)
void pos_loss_main(const float* __restrict__ off, const float* __restrict__ flow,
                   float* __restrict__ partial)
{
    const int g  = blockIdx.x * BLK + threadIdx.x;   // pixel id
    const int b  = g >> HW_BITS;
    const int hw = g & (HW_ - 1);
    const float* offb = off  + ((size_t)b * (2 * NOFF)) * HW_ + hw;
    const float* flb  = flow + ((size_t)b * 8) * HW_ + hw;

    // Issue all 23 loads up front (ILP); lane-adjacent => fully coalesced dwords.
    float f[NFLOW + 1];
#pragma unroll
    for (int j = 0; j <= NFLOW; ++j) f[j] = flb[(size_t)j * HW_];
    float xs[NOFF], ys[NOFF];
#pragma unroll
    for (int i = 0; i < NOFF; ++i) {
        xs[i] = offb[(size_t)i * HW_];
        ys[i] = offb[(size_t)(i + NOFF) * HW_];
    }

    // Per-flow invariants: u, v, u*v, 1/(u*u+v*v).
    float uv_[NFLOW], r_[NFLOW];
#pragma unroll
    for (int j = 0; j < NFLOW; ++j) {
        const float u = f[j], v = f[j + 1];
        uv_[j] = u * v;
        r_[j]  = __builtin_amdgcn_rcpf(fmaf(u, u, v * v));
    }

    float acc = 0.f;
#pragma unroll
    for (int i = 0; i < NOFF; ++i) {
        const float x  = xs[i], y = ys[i];
        const float x2 = x * x;
        const float d1sq = fmaf(y, y, x2);           // x^2 + y^2
        float m2 = 1e30f;                            // min over j of md^2
#pragma unroll
        for (int j = 0; j < NFLOW; ++j) {
            const float u = f[j], v = f[j + 1];
            const float r = r_[j];
            // x0 = (u*x^2 + u*v*y) / uu
            const float x0  = fmaf(u, x2, uv_[j] * y) * r;
            // inside <=> min(0,u) <= x0 <= max(0,u) <=> x0*(x0-u) <= 0
            const float ins = x0 * (x0 - u);
            // perp^2 = (v*x - u*y)^2 / uu
            const float t   = fmaf(v, x, -(u * y));
            const float p2  = (t * t) * r;
            const float dx = x - u, dy = y - v;
            const float d2sq = fmaf(dy, dy, dx * dx);
            const float e2  = fminf(d1sq, d2sq);
            const float md2 = (ins <= 0.f) ? p2 : e2;
            m2 = fminf(m2, md2);
        }
        acc += __builtin_amdgcn_sqrtf(m2);
    }

    // Block reduction: wave64 shuffle tree -> LDS -> one partial per block.
#pragma unroll
    for (int o = 32; o > 0; o >>= 1) acc += __shfl_down(acc, o, 64);
    __shared__ float sm[BLK / 64];
    const int lane = threadIdx.x & 63, wid = threadIdx.x >> 6;
    if (lane == 0) sm[wid] = acc;
    __syncthreads();
    if (threadIdx.x == 0)
        partial[blockIdx.x] = sm[0] + sm[1] + sm[2] + sm[3];
}

__global__ __launch_bounds__(BLK)
void pos_loss_reduce(const float* __restrict__ partial, float* __restrict__ out)
{
    float s = 0.f;
#pragma unroll
    for (int k = 0; k < GRID1 / BLK; ++k)
        s += partial[k * BLK + (int)threadIdx.x];
#pragma unroll
    for (int o = 32; o > 0; o >>= 1) s += __shfl_down(s, o, 64);
    __shared__ float sm[BLK / 64];
    const int lane = threadIdx.x & 63, wid = threadIdx.x >> 6;
    if (lane == 0) sm[wid] = s;
    __syncthreads();
    if (threadIdx.x == 0)
        out[0] = (sm[0] + sm[1] + sm[2] + sm[3]) * (1.0f / (9.0f * (float)HW_));
}

extern "C" void kernel_launch(void* const* d_in, const int* in_sizes, int n_in,
                              void* d_out, int out_size, void* d_ws, size_t ws_size,
                              hipStream_t stream) {
    const float* offset = (const float*)d_in[0];   // [4,18,512,512]
    const float* flow   = (const float*)d_in[1];   // [4,8,512,512]
    float* partial = (float*)d_ws;                 // GRID1 floats
    float* out     = (float*)d_out;                // 1 float

    pos_loss_main<<<GRID1, BLK, 0, stream>>>(offset, flow, partial);
    pos_loss_reduce<<<1, BLK, 0, stream>>>(partial, out);
}

// Round 3
// 26.688 us; speedup vs baseline: 1.5505x; 1.0629x over previous
//
#include <hip/hip_runtime.h>

// PositionLossVal: offset [4,18,512,512] f32, optical_flow [4,8,512,512] f32 -> scalar f32.
// Per pixel: x=off[i], y=off[i+9] (i<9); u=flow[j], v=flow[j+1] (j<4).
// md = inside ? perp : min(d1,d2); min over j, mean over i, sum over b,h,w, /(h*w).
// min over j in squared domain -> 1 sqrt per (pixel,i).
// inside test: x0*(x0-u)<=0  <=>  num*(num-u*uu)<=0 with num = u*x^2 + u*v*y (uu>0).

#define HW_BITS 18
#define HW_ (1 << HW_BITS)          // 512*512
#define NOFF 9
#define NFLOW 4
#define NPIX (4 * HW_)              // 1,048,576 pixels
#define PPT 2                       // pixels per thread (float2 loads)
#define BLK 256
#define GRID1 (NPIX / PPT / BLK)    // 2048 blocks

__global__ __launch_bounds__(BLK, 4)   // cap VGPR at 128 -> >=4 waves/SIMD
void pos_loss_main(const float* __restrict__ off, const float* __restrict__ flow,
                   float* __restrict__ partial)
{
    const int t  = blockIdx.x * BLK + threadIdx.x;
    const int g  = t * PPT;                          // first pixel (pair stays in one image)
    const int b  = g >> HW_BITS;
    const int hw = g & (HW_ - 1);
    const float* offb = off  + ((size_t)b * (2 * NOFF)) * HW_ + hw;
    const float* flb  = flow + ((size_t)b * 8) * HW_ + hw;

    // Flow channels 0..4, 8B vector loads (512B per wave-instruction).
    float2 f2[NFLOW + 1];
#pragma unroll
    for (int j = 0; j <= NFLOW; ++j)
        f2[j] = *reinterpret_cast<const float2*>(flb + (size_t)j * HW_);

    // Offset channels: all 18 as float2 (issued up front for ILP).
    float2 xs2[NOFF], ys2[NOFF];
#pragma unroll
    for (int i = 0; i < NOFF; ++i) {
        xs2[i] = *reinterpret_cast<const float2*>(offb + (size_t)i * HW_);
        ys2[i] = *reinterpret_cast<const float2*>(offb + (size_t)(i + NOFF) * HW_);
    }

    // Per-(px,j) invariants: u*v, 1/uu, u*uu.
    float uv_[PPT][NFLOW], r_[PPT][NFLOW], uuu_[PPT][NFLOW];
#pragma unroll
    for (int j = 0; j < NFLOW; ++j) {
        const float up[PPT] = {f2[j].x, f2[j].y};
        const float vp[PPT] = {f2[j + 1].x, f2[j + 1].y};
#pragma unroll
        for (int p = 0; p < PPT; ++p) {
            const float u = up[p], v = vp[p];
            const float uu = fmaf(u, u, v * v);
            uv_[p][j]  = u * v;
            r_[p][j]   = __builtin_amdgcn_rcpf(uu);
            uuu_[p][j] = u * uu;
        }
    }

    float acc = 0.f;
#pragma unroll
    for (int i = 0; i < NOFF; ++i) {
        const float xp[PPT] = {xs2[i].x, xs2[i].y};
        const float yp[PPT] = {ys2[i].x, ys2[i].y};
#pragma unroll
        for (int p = 0; p < PPT; ++p) {
            const float x  = xp[p], y = yp[p];
            const float x2 = x * x;
            const float d1sq = fmaf(y, y, x2);
            float m2 = 1e30f;
#pragma unroll
            for (int j = 0; j < NFLOW; ++j) {
                const float u = (p == 0) ? f2[j].x : f2[j].y;
                const float v = (p == 0) ? f2[j + 1].x : f2[j + 1].y;
                const float num = fmaf(u, x2, uv_[p][j] * y);      // x0 * uu
                const float ins = num * (num - uuu_[p][j]);        // sign == x0*(x0-u)
                const float tt  = fmaf(v, x, -(u * y));
                const float p2  = (tt * tt) * r_[p][j];
                const float dx = x - u, dy = y - v;
                const float d2sq = fmaf(dy, dy, dx * dx);
                const float e2  = fminf(d1sq, d2sq);
                const float md2 = (ins <= 0.f) ? p2 : e2;
                m2 = fminf(m2, md2);
            }
            acc += __builtin_amdgcn_sqrtf(m2);
        }
    }

    // Block reduction: wave64 shuffle tree -> LDS -> one partial per block.
#pragma unroll
    for (int o = 32; o > 0; o >>= 1) acc += __shfl_down(acc, o, 64);
    __shared__ float sm[BLK / 64];
    const int lane = threadIdx.x & 63, wid = threadIdx.x >> 6;
    if (lane == 0) sm[wid] = acc;
    __syncthreads();
    if (threadIdx.x == 0)
        partial[blockIdx.x] = sm[0] + sm[1] + sm[2] + sm[3];
}

__global__ __launch_bounds__(BLK)
void pos_loss_reduce(const float* __restrict__ partial, float* __restrict__ out)
{
    float s = 0.f;
#pragma unroll
    for (int k = 0; k < GRID1 / BLK; ++k)
        s += partial[k * BLK + (int)threadIdx.x];
#pragma unroll
    for (int o = 32; o > 0; o >>= 1) s += __shfl_down(s, o, 64);
    __shared__ float sm[BLK / 64];
    const int lane = threadIdx.x & 63, wid = threadIdx.x >> 6;
    if (lane == 0) sm[wid] = s;
    __syncthreads();
    if (threadIdx.x == 0)
        out[0] = (sm[0] + sm[1] + sm[2] + sm[3]) * (1.0f / (9.0f * (float)HW_));
}

extern "C" void kernel_launch(void* const* d_in, const int* in_sizes, int n_in,
                              void* d_out, int out_size, void* d_ws, size_t ws_size,
                              hipStream_t stream) {
    const float* offset = (const float*)d_in[0];   // [4,18,512,512]
    const float* flow   = (const float*)d_in[1];   // [4,8,512,512]
    float* partial = (float*)d_ws;                 // GRID1 floats
    float* out     = (float*)d_out;                // 1 float

    pos_loss_main<<<GRID1, BLK, 0, stream>>>(offset, flow, partial);
    pos_loss_reduce<<<1, BLK, 0, stream>>>(partial, out);
}